// Round 7
// baseline (2167.817 us; speedup 1.0000x reference)
//
#include <hip/hip_runtime.h>

// LSTM_27152783245909 — persistent-recurrence LSTM for MI355X (gfx950)
// R10: intra-XCD recurrence. R4-R9 established that the ~3.3us/step floor is
// the cross-XCD MALL rendezvous itself (volume/transactions/pressure/caching
// all null). Fix: re-partition so the exchange never leaves an XCD.
//   * XCD x (= blockIdx%8 under the empirical round-robin dispatch of a
//     256-block 1-block/CU launch) owns batch rows [8x,8x+8) ENTIRELY.
//     Block: 8 rows x 32 units (N=128 gate cols, K=1536, M=8-in-16 MFMA).
//     h-exchange = 16KB/step among the 32 same-XCD blocks.
//   * fast path: producers plain-store a full-T ring slice (lands in own
//     XCD's L2); consumers poll with sc0 loads (L1-bypass, L2-served,
//     ~200cy). bit14==0 = written (|h|<1); poison 0xFF fails.
//   * safety: producers ALSO publish to the R8-proven 2-slot parity-tagged
//     MALL buffer (sc0sc1). Consumers: 48-round bounded ring poll -> on
//     failure, unbounded MALL poll; >=4 granule-failures -> sticky MALL.
//     Liveness unconditional; wrong-mapping only costs speed (~R8 perf).
//   * stale accepts (rocprof replay without memset) are bit-identical by
//     determinism — proven benign by R9 passing.

#define T_ 256
#define FASTROUNDS 48

typedef __attribute__((ext_vector_type(8))) short bf16x8;
typedef __attribute__((ext_vector_type(4))) float floatx4;
typedef __attribute__((ext_vector_type(4))) int intx4;

__device__ __forceinline__ unsigned short f2bf(float f) {
  unsigned u = __builtin_bit_cast(unsigned, f);
  u += 0x7FFFu + ((u >> 16) & 1u);   // round-nearest-even
  return (unsigned short)(u >> 16);
}

__device__ __forceinline__ float sigm(float x) { return 1.0f / (1.0f + __expf(-x)); }
// tanh(x) = 2*sigm(2x) - 1; exp-based, saturates correctly, no NaN.
__device__ __forceinline__ float tanh_fast(float x) {
  return __builtin_fmaf(2.f, sigm(2.f * x), -1.f);
}

// ---------------- W_out fp32 -> bf16 (512x1024) ----------------
__global__ void cvt_w(const float* __restrict__ w, unsigned short* __restrict__ o) {
  const size_t g = (size_t)blockIdx.x * 256 + threadIdx.x;
  const float* s = w + g * 8;
  bf16x8 v;
#pragma unroll
  for (int i = 0; i < 8; ++i) v[i] = (short)f2bf(s[i]);
  *(bf16x8*)(o + g * 8) = v;
}

// ---------------- x[B=64, I=512, T=256] fp32 -> xT[T,B,I] bf16 ----------------
__global__ void transpose_x(const float* __restrict__ x, unsigned short* __restrict__ xT) {
  __shared__ float tile[32][33];
  const int b = blockIdx.z, i0 = blockIdx.y * 32, t0 = blockIdx.x * 32;
  const int tx = threadIdx.x & 31, ty = threadIdx.x >> 5;
#pragma unroll
  for (int p = 0; p < 4; ++p) {
    const int i = ty + p * 8;
    tile[i][tx] = x[((size_t)b * 512 + i0 + i) * 256 + t0 + tx];
  }
  __syncthreads();
#pragma unroll
  for (int p = 0; p < 4; ++p) {
    const int t = ty + p * 8;
    xT[((size_t)(t0 + t) * 64 + b) * 512 + i0 + tx] = f2bf(tile[tx][t]);
  }
}

// ---------------- persistent recurrence ----------------
// 256 blocks x 512 thr, 1 block/CU. Block: xg = blockIdx%8 (XCD under
// round-robin; batch rows [8xg,8xg+8)), ngb = blockIdx>>3 (units
// [32ngb,32ngb+32)). Wave (nh = n-half of 128 gate cols, kq = K quarter).
// Weights in VGPRs (192/lane), c in thread registers.
__global__ __launch_bounds__(512, 1) void lstm_rec(
    const float* __restrict__ Whh, const float* __restrict__ Wih,
    const float* __restrict__ bih, const float* __restrict__ bhh,
    const float* __restrict__ h0, const float* __restrict__ c0,
    const unsigned short* __restrict__ xT,
    unsigned short* __restrict__ hbuf,   // [2][64][1024] bf16 MALL copy (sc0sc1)
    unsigned short* __restrict__ hring,  // [256][8][8][1024] bf16 ring (plain/L2)
    unsigned short* __restrict__ call,   // [256][64][1024] bf16 (normal cached)
    const int have_ring)
{
  const int tid = threadIdx.x;
  const int lane = tid & 63;
  const int wv = tid >> 6;           // 0..7
  const int nh = wv & 1, kq = wv >> 1;
  const int xg = blockIdx.x & 7;     // XCD-group: batch rows [8xg, 8xg+8)
  const int ngb = blockIdx.x >> 3;   // unit group: [32ngb, 32ngb+32)
  const int l15 = lane & 15, lq = lane >> 4;
  const int hrow = l15 & 7;          // A-row (rows 8-15 duplicate 0-7; C rows
                                     // 8-15 are discarded, so this is safe)

  __shared__ unsigned short hlds[8 * 1032];   // 8 rows, stride 1032 (+8 pad)
  __shared__ float gpart[4][8][132];          // [kq][row][gatecol 0..127]

  // persistent B fragments: 4 n-tiles x 12 ksteps = 192 VGPRs/lane.
  // block gate-col c = nh*64 + a*16 + l15 ; gate g=c>>5, unit u=c&31;
  // weight column = g*1024 + ngb*32 + u. K: [0,1024)=Whh, [1024,1536)=Wih.
  bf16x8 bfrag[4][12];
#pragma unroll
  for (int a = 0; a < 4; ++a) {
    const int c = nh * 64 + a * 16 + l15;
    const int wcol = (c >> 5) * 1024 + ngb * 32 + (c & 31);
#pragma unroll
    for (int ks = 0; ks < 12; ++ks) {
      const int kg = kq * 384 + ks * 32 + lq * 8;   // never straddles 1024
      const float* s = (kg < 1024) ? (Whh + (size_t)wcol * 1024 + kg)
                                   : (Wih + (size_t)wcol * 512 + (kg - 1024));
      bf16x8 v;
#pragma unroll
      for (int i = 0; i < 8; ++i) v[i] = (short)f2bf(s[i]);
      bfrag[a][ks] = v;
    }
  }

  // per-thread cell state (waves 0..3): cell (batch m_loc, unit j)
  const int m_loc = tid >> 5, j = tid & 31;
  const int row_g = xg * 8 + m_loc;       // global batch row
  const int unit = ngb * 32 + j;
  float c_reg = 0.f, bs0 = 0.f, bs1 = 0.f, bs2 = 0.f, bs3 = 0.f;
  if (tid < 256) {
    c_reg = c0[unit];
    bs0 = bih[unit] + bhh[unit];
    bs1 = bih[1024 + unit] + bhh[1024 + unit];
    bs2 = bih[2048 + unit] + bhh[2048 + unit];
    bs3 = bih[3072 + unit] + bhh[3072 + unit];
  }

  int fails = have_ring ? 0 : 1000;       // >=4 -> sticky MALL path

  for (int t = 0; t < T_; ++t) {
    floatx4 zero = {0.f, 0.f, 0.f, 0.f};
    floatx4 acc[4] = {zero, zero, zero, zero};

    // ---- x-part (no dependence on h_{t-1}; overlaps peers' publishes) ----
    const unsigned short* bx = xT + ((size_t)t * 64 + xg * 8 + hrow) * 512;
#pragma unroll
    for (int ks = 0; ks < 12; ++ks) {
      const int kg = kq * 384 + ks * 32 + lq * 8;
      if (kg >= 1024) {
        const bf16x8 af = *(const bf16x8*)(bx + (kg - 1024));
#pragma unroll
        for (int a = 0; a < 4; ++a)
          acc[a] = __builtin_amdgcn_mfma_f32_16x16x32_bf16(af, bfrag[a][ks], acc[a], 0, 0, 0);
      }
    }

    // ---- obtain h_{t-1}[8 rows][1024] -> LDS (1024 granules of 16B) ----
    if (t == 0) {
      // h_{-1} = h0 broadcast over batch (fp32 input; bypasses tag paths)
#pragma unroll
      for (int p = 0; p < 2; ++p) {
        const int g = tid + p * 512;
        const int row8 = g >> 7, colu = (g & 127) * 8;
        const float* s = h0 + colu;
        bf16x8 v;
#pragma unroll
        for (int i = 0; i < 8; ++i) v[i] = (short)f2bf(s[i]);
        *(bf16x8*)(hlds + row8 * 1032 + colu) = v;
      }
    } else {
      const int rt = t - 1;
      const unsigned tagpat = ((rt >> 1) & 1) ? 0x40004000u : 0u;
#pragma unroll
      for (int p = 0; p < 2; ++p) {
        const int g = tid + p * 512;
        const int row8 = g >> 7, colu = (g & 127) * 8;
        const unsigned short* rp =
            hring + ((size_t)(rt * 8 + xg) * 8 + row8) * 1024 + colu;
        const unsigned short* mp =
            hbuf + ((t + 1) & 1) * 65536 + (size_t)(xg * 8 + row8) * 1024 + colu;
        intx4 v;
        bool got = false;
        if (fails < 4) {
          // fast path: own-XCD L2 ring (plain-stored by producer; sc0 load
          // bypasses L1). bit14==0 on every short == written.
          for (int r = 0; r < FASTROUNDS; ++r) {
            asm volatile("global_load_dwordx4 %0, %1, off sc0\n\ts_waitcnt vmcnt(0)"
                         : "=v"(v) : "v"(rp) : "memory");
            unsigned bad = 0;
#pragma unroll
            for (int d = 0; d < 4; ++d) bad |= (unsigned)v[d] & 0x40004000u;
            if (!bad) { got = true; break; }
            __builtin_amdgcn_s_sleep(1);
          }
        }
        if (!got) {
          // fallback: R8-proven unbounded MALL poll (parity tags)
          if (fails < 1000) ++fails;
          while (true) {
            asm volatile("global_load_dwordx4 %0, %1, off sc0 sc1\n\ts_waitcnt vmcnt(0)"
                         : "=v"(v) : "v"(mp) : "memory");
            unsigned bad = 0;
#pragma unroll
            for (int d = 0; d < 4; ++d) bad |= ((unsigned)v[d] ^ tagpat) & 0x40004000u;
            if (!bad) break;
            __builtin_amdgcn_s_sleep(1);
          }
#pragma unroll
          for (int d = 0; d < 4; ++d) v[d] &= (int)0xBFFFBFFFu;   // strip parity
        }
        *(intx4*)(hlds + row8 * 1032 + colu) = v;
      }
    }
    __syncthreads();

    // ---- h-part MFMAs from LDS ----
#pragma unroll
    for (int ks = 0; ks < 12; ++ks) {
      const int kg = kq * 384 + ks * 32 + lq * 8;
      if (kg < 1024) {
        const bf16x8 af = *(const bf16x8*)(hlds + hrow * 1032 + kg);
#pragma unroll
        for (int a = 0; a < 4; ++a)
          acc[a] = __builtin_amdgcn_mfma_f32_16x16x32_bf16(af, bfrag[a][ks], acc[a], 0, 0, 0);
      }
    }

    // C layout: col = lane&15, row = (lane>>4)*4 + r ; keep rows 0-7 (lq<2)
    if (lq < 2) {
#pragma unroll
      for (int a = 0; a < 4; ++a)
#pragma unroll
        for (int r = 0; r < 4; ++r)
          gpart[kq][lq * 4 + r][nh * 64 + a * 16 + l15] = acc[a][r];
    }
    __syncthreads();

    if (tid < 256) {
      float gi = bs0, gf = bs1, gg = bs2, go = bs3;
#pragma unroll
      for (int q = 0; q < 4; ++q) {
        gi += gpart[q][m_loc][j];
        gf += gpart[q][m_loc][32 + j];
        gg += gpart[q][m_loc][64 + j];
        go += gpart[q][m_loc][96 + j];
      }
      const float iv = sigm(gi), fv = sigm(gf), gv = tanh_fast(gg), ov = sigm(go);
      c_reg = fv * c_reg + iv * gv;
      const float hv = ov * tanh_fast(c_reg);

      // ---- packed double-publish: 8 lanes -> one dwordx4 ----
      const unsigned hb = (unsigned)f2bf(hv);     // |hv|<1 -> bit14 == 0
      const int base = lane & 56;                 // 8-lane group (same m_loc)
      intx4 pk;
#pragma unroll
      for (int k = 0; k < 4; ++k) {
        const unsigned lo = (unsigned)__shfl((int)hb, base + 2 * k, 64) & 0xFFFFu;
        const unsigned hi = (unsigned)__shfl((int)hb, base + 2 * k + 1, 64);
        pk[k] = (int)(lo | (hi << 16));
      }
      if ((tid & 7) == 0) {
        const int u8 = unit & ~7;
        if (have_ring) {
          // fast: plain store -> own XCD's L2 (consumers sc0-load it)
          *(intx4*)(hring + ((size_t)(t * 8 + xg) * 8 + m_loc) * 1024 + u8) = pk;
        }
        // guaranteed: parity-tagged MALL copy (R8 protocol)
        const unsigned tagmask = ((t >> 1) & 1) ? 0x40004000u : 0u;
        intx4 pk2;
#pragma unroll
        for (int k = 0; k < 4; ++k) pk2[k] = pk[k] | (int)tagmask;
        unsigned short* hp = hbuf + (t & 1) * 65536 + row_g * 1024 + u8;
        asm volatile("global_store_dwordx4 %0, %1, off sc0 sc1"
                     :: "v"(hp), "v"(pk2) : "memory");
      }
      call[((size_t)t * 64 + row_g) * 1024 + unit] = f2bf(c_reg);
    }
    // 2 barriers/step: hlds-fill barrier + gpart barrier (hlds reads all
    // precede the gpart barrier; gpart reads precede the next hlds barrier).
  }
}

// ---------------- output head: logits + softmax, fully parallel over t ----------------
__global__ __launch_bounds__(256, 1) void lstm_head(
    const unsigned short* __restrict__ call,
    const unsigned short* __restrict__ wout,
    const float* __restrict__ bout,
    float* __restrict__ out)
{
  const int tb = blockIdx.x;
  const int lane = threadIdx.x & 63;
  const int wv = threadIdx.x >> 6;
  const int l15 = lane & 15, lq = lane >> 4;

  __shared__ float sred[2][4][64];

  floatx4 zero = {0.f, 0.f, 0.f, 0.f};
  floatx4 acc[4][8];
#pragma unroll
  for (int mt = 0; mt < 4; ++mt)
#pragma unroll
    for (int nt = 0; nt < 8; ++nt) acc[mt][nt] = zero;

  const unsigned short* abase = call + ((size_t)tb * 64 + l15) * 1024 + lq * 8;
  const unsigned short* bbase = wout + ((size_t)(wv * 128 + l15)) * 1024 + lq * 8;

#pragma unroll 2
  for (int ks = 0; ks < 32; ++ks) {
    bf16x8 a[4];
#pragma unroll
    for (int mt = 0; mt < 4; ++mt)
      a[mt] = *(const bf16x8*)(abase + (size_t)mt * 16 * 1024 + ks * 32);
#pragma unroll
    for (int nt = 0; nt < 8; ++nt) {
      const bf16x8 b = *(const bf16x8*)(bbase + (size_t)nt * 16 * 1024 + ks * 32);
#pragma unroll
      for (int mt = 0; mt < 4; ++mt)
        acc[mt][nt] = __builtin_amdgcn_mfma_f32_16x16x32_bf16(a[mt], b, acc[mt][nt], 0, 0, 0);
    }
  }

#pragma unroll
  for (int nt = 0; nt < 8; ++nt) {
    const float bo = bout[wv * 128 + nt * 16 + l15];
#pragma unroll
    for (int mt = 0; mt < 4; ++mt)
#pragma unroll
      for (int r = 0; r < 4; ++r) acc[mt][nt][r] += bo;
  }

  float rmax[4][4];
#pragma unroll
  for (int mt = 0; mt < 4; ++mt)
#pragma unroll
    for (int r = 0; r < 4; ++r) {
      float m = acc[mt][0][r];
#pragma unroll
      for (int nt = 1; nt < 8; ++nt) m = fmaxf(m, acc[mt][nt][r]);
      m = fmaxf(m, __shfl_xor(m, 1, 64));
      m = fmaxf(m, __shfl_xor(m, 2, 64));
      m = fmaxf(m, __shfl_xor(m, 4, 64));
      m = fmaxf(m, __shfl_xor(m, 8, 64));
      rmax[mt][r] = m;
    }
  if (l15 == 0) {
#pragma unroll
    for (int mt = 0; mt < 4; ++mt)
#pragma unroll
      for (int r = 0; r < 4; ++r) sred[0][wv][mt * 16 + lq * 4 + r] = rmax[mt][r];
  }
  __syncthreads();
  float gmax[4][4], rsum[4][4];
#pragma unroll
  for (int mt = 0; mt < 4; ++mt)
#pragma unroll
    for (int r = 0; r < 4; ++r) {
      const int rw = mt * 16 + lq * 4 + r;
      gmax[mt][r] = fmaxf(fmaxf(sred[0][0][rw], sred[0][1][rw]),
                          fmaxf(sred[0][2][rw], sred[0][3][rw]));
      rsum[mt][r] = 0.f;
    }
#pragma unroll
  for (int mt = 0; mt < 4; ++mt)
#pragma unroll
    for (int nt = 0; nt < 8; ++nt)
#pragma unroll
      for (int r = 0; r < 4; ++r) {
        const float e = __expf(acc[mt][nt][r] - gmax[mt][r]);
        acc[mt][nt][r] = e;
        rsum[mt][r] += e;
      }
#pragma unroll
  for (int mt = 0; mt < 4; ++mt)
#pragma unroll
    for (int r = 0; r < 4; ++r) {
      float s = rsum[mt][r];
      s += __shfl_xor(s, 1, 64);
      s += __shfl_xor(s, 2, 64);
      s += __shfl_xor(s, 4, 64);
      s += __shfl_xor(s, 8, 64);
      rsum[mt][r] = s;
    }
  if (l15 == 0) {
#pragma unroll
    for (int mt = 0; mt < 4; ++mt)
#pragma unroll
      for (int r = 0; r < 4; ++r) sred[1][wv][mt * 16 + lq * 4 + r] = rsum[mt][r];
  }
  __syncthreads();
#pragma unroll
  for (int mt = 0; mt < 4; ++mt)
#pragma unroll
    for (int r = 0; r < 4; ++r) {
      const int rw = mt * 16 + lq * 4 + r;
      const float inv = 1.0f / (sred[1][0][rw] + sred[1][1][rw] +
                                sred[1][2][rw] + sred[1][3][rw]);
      float* orow = out + ((size_t)tb * 64 + rw) * 512 + wv * 128 + l15;
#pragma unroll
      for (int nt = 0; nt < 8; ++nt) orow[nt * 16] = acc[mt][nt][r] * inv;
    }
}

// ---------------- launch ----------------
extern "C" void kernel_launch(void* const* d_in, const int* in_sizes, int n_in,
                              void* d_out, int out_size, void* d_ws, size_t ws_size,
                              hipStream_t stream) {
  const float* x    = (const float*)d_in[0];
  const float* Wih  = (const float*)d_in[1];
  const float* Whh  = (const float*)d_in[2];
  const float* bih  = (const float*)d_in[3];
  const float* bhh  = (const float*)d_in[4];
  const float* Wout = (const float*)d_in[5];
  const float* bout = (const float*)d_in[6];
  const float* h0   = (const float*)d_in[7];
  const float* c0   = (const float*)d_in[8];
  float* out = (float*)d_out;

  char* ws = (char*)d_ws;
  unsigned short* hbuf  = (unsigned short*)(ws + 4096);         //   256 KB (MALL copy)
  unsigned short* woutb = (unsigned short*)(ws + 266240);       //     1 MB
  unsigned short* xT    = (unsigned short*)(ws + 1314816);      //    16 MB
  unsigned short* call  = (unsigned short*)(ws + 18092032);     //    32 MB
  unsigned short* hring = (unsigned short*)(ws + 51646464);     //    32 MB (ring)

  const size_t need = 51646464ull + 33554432ull;   // 85,200,896 B (R9-proven)
  const int have_ring = (ws_size >= need) ? 1 : 0;

  // poison: 0xFFFF has bit14=1 -> "not written" for the ring, and != parity
  // tag 0 for hbuf's first polls.
  hipMemsetAsync(hbuf, 0xFF, 262144, stream);
  if (have_ring) hipMemsetAsync(hring, 0xFF, 33554432, stream);
  cvt_w<<<256, 256, 0, stream>>>(Wout, woutb);
  transpose_x<<<dim3(8, 16, 64), 256, 0, stream>>>(x, xT);
  lstm_rec<<<256, 512, 0, stream>>>(Whh, Wih, bih, bhh, h0, c0, xT, hbuf, hring, call, have_ring);
  lstm_head<<<256, 256, 0, stream>>>(call, woutb, bout, out);
}

// Round 8
// 1833.369 us; speedup vs baseline: 1.1824x; 1.1824x over previous
//
#include <hip/hip_runtime.h>

// LSTM_27152783245909 — persistent-recurrence LSTM for MI355X (gfx950)
// R11: intra-XCD recurrence, done with the PROVEN exchange discipline.
// R10's regression was protocol, not partition: serial per-granule polls,
// no sample gate, and a full-T ring whose first touch per granule was a
// compulsory HBM miss. R11 keeps R10's partition (XCD xg = blockIdx&7 owns
// batch rows [8xg,8xg+8); block = 8 rows x 32 units; weights resident) and:
//  * hx[2][8][8][1024] 2-slot ring, 32KB/XCD -> L2-RESIDENT; polls are L2
//    hits. Parity bit14 tags; per-location coherence makes slot reuse safe
//    (an accepted parity can only be the latest same-address write h_{t-1}).
//  * R8 discipline: wave-0 sample gate (1 granule per same-XCD producer,
//    sc0, bounded 256 rounds + sleep) -> barrier -> batched concurrent
//    2-granule/thread sc0 bulk read, tag-verified.
//  * placement check: HW_REG_XCC_ID == blockIdx&7. Misplaced blocks never
//    write the ring (granules stay poisoned -> consumers' gate times out ->
//    group converges to the R8-proven MALL path on hbuf; producers always
//    double-publish there). Liveness+correctness unconditional.

#define T_ 256
#define GATE_ROUNDS 256

typedef __attribute__((ext_vector_type(8))) short bf16x8;
typedef __attribute__((ext_vector_type(4))) float floatx4;
typedef __attribute__((ext_vector_type(4))) int intx4;

__device__ __forceinline__ unsigned short f2bf(float f) {
  unsigned u = __builtin_bit_cast(unsigned, f);
  u += 0x7FFFu + ((u >> 16) & 1u);   // round-nearest-even
  return (unsigned short)(u >> 16);
}

__device__ __forceinline__ float sigm(float x) { return 1.0f / (1.0f + __expf(-x)); }
// tanh(x) = 2*sigm(2x) - 1; exp-based, saturates correctly, no NaN.
__device__ __forceinline__ float tanh_fast(float x) {
  return __builtin_fmaf(2.f, sigm(2.f * x), -1.f);
}

// ---------------- W_out fp32 -> bf16 (512x1024) ----------------
__global__ void cvt_w(const float* __restrict__ w, unsigned short* __restrict__ o) {
  const size_t g = (size_t)blockIdx.x * 256 + threadIdx.x;
  const float* s = w + g * 8;
  bf16x8 v;
#pragma unroll
  for (int i = 0; i < 8; ++i) v[i] = (short)f2bf(s[i]);
  *(bf16x8*)(o + g * 8) = v;
}

// ---------------- x[B=64, I=512, T=256] fp32 -> xT[T,B,I] bf16 ----------------
__global__ void transpose_x(const float* __restrict__ x, unsigned short* __restrict__ xT) {
  __shared__ float tile[32][33];
  const int b = blockIdx.z, i0 = blockIdx.y * 32, t0 = blockIdx.x * 32;
  const int tx = threadIdx.x & 31, ty = threadIdx.x >> 5;
#pragma unroll
  for (int p = 0; p < 4; ++p) {
    const int i = ty + p * 8;
    tile[i][tx] = x[((size_t)b * 512 + i0 + i) * 256 + t0 + tx];
  }
  __syncthreads();
#pragma unroll
  for (int p = 0; p < 4; ++p) {
    const int t = ty + p * 8;
    xT[((size_t)(t0 + t) * 64 + b) * 512 + i0 + tx] = f2bf(tile[tx][t]);
  }
}

// ---------------- persistent recurrence ----------------
// 256 blocks x 512 thr, 1 block/CU. xg = blockIdx&7 (XCD under round-robin;
// batch rows [8xg,8xg+8)), ngb = blockIdx>>3 (units [32ngb,32ngb+32)).
// Wave (nh = n-half of 128 gate cols, kq = K quarter of 1536).
__global__ __launch_bounds__(512, 1) void lstm_rec(
    const float* __restrict__ Whh, const float* __restrict__ Wih,
    const float* __restrict__ bih, const float* __restrict__ bhh,
    const float* __restrict__ h0, const float* __restrict__ c0,
    const unsigned short* __restrict__ xT,
    unsigned short* __restrict__ hbuf,   // [2][64][1024] bf16 MALL copy (sc0sc1)
    unsigned short* __restrict__ hx,     // [2][8][8][1024] bf16 L2 ring (plain/sc0)
    unsigned short* __restrict__ call)   // [256][64][1024] bf16 (normal cached)
{
  const int tid = threadIdx.x;
  const int lane = tid & 63;
  const int wv = tid >> 6;           // 0..7
  const int nh = wv & 1, kq = wv >> 1;
  const int xg = blockIdx.x & 7;     // XCD-group: batch rows [8xg, 8xg+8)
  const int ngb = blockIdx.x >> 3;   // unit group: [32ngb, 32ngb+32)
  const int l15 = lane & 15, lq = lane >> 4;
  const int hrow = l15 & 7;          // A rows 8-15 duplicate 0-7; C rows 8-15
                                     // are discarded (lq<2 kept) -- safe.

  __shared__ unsigned short hlds[8 * 1032];   // 8 rows, stride 1032 (+8 pad)
  __shared__ float gpart[4][8][132];          // [kq][row][gatecol 0..127]
  __shared__ int s_mode;                      // 0 = L2 ring fast, 1 = MALL

  if (tid == 0) {
    unsigned xcc;
    asm volatile("s_getreg_b32 %0, hwreg(HW_REG_XCC_ID)" : "=s"(xcc));
    s_mode = (((unsigned)blockIdx.x & 7u) == (xcc & 7u)) ? 0 : 1;
  }

  // persistent B fragments: 4 n-tiles x 12 ksteps (compiler may use AGPRs).
  // gate-col c = nh*64+a*16+l15; weight col = (c>>5)*1024 + ngb*32 + (c&31).
  bf16x8 bfrag[4][12];
#pragma unroll
  for (int a = 0; a < 4; ++a) {
    const int c = nh * 64 + a * 16 + l15;
    const int wcol = (c >> 5) * 1024 + ngb * 32 + (c & 31);
#pragma unroll
    for (int ks = 0; ks < 12; ++ks) {
      const int kg = kq * 384 + ks * 32 + lq * 8;   // never straddles 1024
      const float* s = (kg < 1024) ? (Whh + (size_t)wcol * 1024 + kg)
                                   : (Wih + (size_t)wcol * 512 + (kg - 1024));
      bf16x8 v;
#pragma unroll
      for (int i = 0; i < 8; ++i) v[i] = (short)f2bf(s[i]);
      bfrag[a][ks] = v;
    }
  }

  // per-thread cell state (waves 0..3): cell (batch m_loc, unit j)
  const int m_loc = tid >> 5, j = tid & 31;
  const int row_g = xg * 8 + m_loc;       // global batch row
  const int unit = ngb * 32 + j;
  float c_reg = 0.f, bs0 = 0.f, bs1 = 0.f, bs2 = 0.f, bs3 = 0.f;
  if (tid < 256) {
    c_reg = c0[unit];
    bs0 = bih[unit] + bhh[unit];
    bs1 = bih[1024 + unit] + bhh[1024 + unit];
    bs2 = bih[2048 + unit] + bhh[2048 + unit];
    bs3 = bih[3072 + unit] + bhh[3072 + unit];
  }
  __syncthreads();
  const bool placed = (s_mode == 0);      // static placement (ring-write gate)

  for (int t = 0; t < T_; ++t) {
    floatx4 zero = {0.f, 0.f, 0.f, 0.f};
    floatx4 acc[4] = {zero, zero, zero, zero};

    // ---- x-part (no dependence on h_{t-1}; overlaps peers' publishes) ----
    const unsigned short* bx = xT + ((size_t)t * 64 + xg * 8 + hrow) * 512;
#pragma unroll
    for (int ks = 0; ks < 12; ++ks) {
      const int kg = kq * 384 + ks * 32 + lq * 8;
      if (kg >= 1024) {
        const bf16x8 af = *(const bf16x8*)(bx + (kg - 1024));
#pragma unroll
        for (int a = 0; a < 4; ++a)
          acc[a] = __builtin_amdgcn_mfma_f32_16x16x32_bf16(af, bfrag[a][ks], acc[a], 0, 0, 0);
      }
    }

    // ---- obtain h_{t-1}[8 rows][1024] -> LDS ----
    if (t == 0) {
      // h_{-1} = h0 broadcast (fp32 input; bypasses tag paths)
#pragma unroll
      for (int p = 0; p < 2; ++p) {
        const int g = tid + p * 512;
        const int row8 = g >> 7, colu = (g & 127) * 8;
        const float* s = h0 + colu;
        bf16x8 v;
#pragma unroll
        for (int i = 0; i < 8; ++i) v[i] = (short)f2bf(s[i]);
        *(bf16x8*)(hlds + row8 * 1032 + colu) = v;
      }
    } else {
      const int slot = (t + 1) & 1;                       // = (t-1)&1
      const unsigned tagpat = (((t - 1) >> 1) & 1) ? 0x40004000u : 0u;
      const unsigned short* rbase = hx + ((size_t)(slot * 8 + xg)) * 8192;
      const unsigned short* mbase = hbuf + (size_t)slot * 65536 + (size_t)(xg * 8) * 1024;

      if (s_mode == 0) {
        // -- fast gate: wave 0, lane<32 samples producer ngb'=lane's first
        //    granule (row 0, unit 32*lane) from own-XCD L2 (sc0).
        if (wv == 0) {
          bool ok = false;
          const unsigned short* sp = rbase + (size_t)lane * 32;
          for (int r = 0; r < GATE_ROUNDS; ++r) {
            intx4 sv;
            asm volatile("global_load_dwordx4 %0, %1, off sc0\n\ts_waitcnt vmcnt(0)"
                         : "=v"(sv) : "v"(sp) : "memory");
            unsigned bad = 0;
#pragma unroll
            for (int d = 0; d < 4; ++d) bad |= ((unsigned)sv[d] ^ tagpat) & 0x40004000u;
            if (__all(lane < 32 ? (bad == 0) : true)) { ok = true; break; }
            __builtin_amdgcn_s_sleep(1);
          }
          if (!ok && lane == 0) s_mode = 1;   // sticky MALL (liveness)
        }
        __syncthreads();
      }

      intx4 v0, v1;
      const int r0 = tid >> 7, c0b = (tid & 127) * 8;
      const int r1 = (tid + 512) >> 7, c1b = ((tid + 512) & 127) * 8;
      if (s_mode == 0) {
        // -- fast bulk: 2 concurrent sc0 granule loads from own-XCD L2.
        const unsigned short* p0 = rbase + (size_t)r0 * 1024 + c0b;
        const unsigned short* p1 = rbase + (size_t)r1 * 1024 + c1b;
        while (true) {
          asm volatile(
              "global_load_dwordx4 %0, %2, off sc0\n\t"
              "global_load_dwordx4 %1, %3, off sc0\n\t"
              "s_waitcnt vmcnt(0)"
              : "=v"(v0), "=v"(v1) : "v"(p0), "v"(p1) : "memory");
          unsigned bad = 0;
#pragma unroll
          for (int d = 0; d < 4; ++d) {
            bad |= ((unsigned)v0[d] ^ tagpat) & 0x40004000u;
            bad |= ((unsigned)v1[d] ^ tagpat) & 0x40004000u;
          }
          if (!bad) break;
          __builtin_amdgcn_s_sleep(1);
        }
      } else {
        // -- MALL path (R8-proven): wave-0 unbounded sample gate + barrier +
        //    batched sc0sc1 bulk.
        if (wv == 0) {
          const unsigned short* sp = mbase + (size_t)lane * 32;
          while (true) {
            intx4 sv;
            asm volatile("global_load_dwordx4 %0, %1, off sc0 sc1\n\ts_waitcnt vmcnt(0)"
                         : "=v"(sv) : "v"(sp) : "memory");
            unsigned bad = 0;
#pragma unroll
            for (int d = 0; d < 4; ++d) bad |= ((unsigned)sv[d] ^ tagpat) & 0x40004000u;
            if (__all(lane < 32 ? (bad == 0) : true)) break;
            __builtin_amdgcn_s_sleep(1);
          }
        }
        __syncthreads();
        const unsigned short* p0 = mbase + (size_t)r0 * 1024 + c0b;
        const unsigned short* p1 = mbase + (size_t)r1 * 1024 + c1b;
        while (true) {
          asm volatile(
              "global_load_dwordx4 %0, %2, off sc0 sc1\n\t"
              "global_load_dwordx4 %1, %3, off sc0 sc1\n\t"
              "s_waitcnt vmcnt(0)"
              : "=v"(v0), "=v"(v1) : "v"(p0), "v"(p1) : "memory");
          unsigned bad = 0;
#pragma unroll
          for (int d = 0; d < 4; ++d) {
            bad |= ((unsigned)v0[d] ^ tagpat) & 0x40004000u;
            bad |= ((unsigned)v1[d] ^ tagpat) & 0x40004000u;
          }
          if (!bad) break;
          __builtin_amdgcn_s_sleep(1);
        }
      }
#pragma unroll
      for (int d = 0; d < 4; ++d) { v0[d] &= (int)0xBFFFBFFFu; v1[d] &= (int)0xBFFFBFFFu; }
      *(intx4*)(hlds + r0 * 1032 + c0b) = v0;
      *(intx4*)(hlds + r1 * 1032 + c1b) = v1;
    }
    __syncthreads();

    // ---- h-part MFMAs from LDS ----
#pragma unroll
    for (int ks = 0; ks < 12; ++ks) {
      const int kg = kq * 384 + ks * 32 + lq * 8;
      if (kg < 1024) {
        const bf16x8 af = *(const bf16x8*)(hlds + hrow * 1032 + kg);
#pragma unroll
        for (int a = 0; a < 4; ++a)
          acc[a] = __builtin_amdgcn_mfma_f32_16x16x32_bf16(af, bfrag[a][ks], acc[a], 0, 0, 0);
      }
    }

    // C layout: col = lane&15, row = (lane>>4)*4 + r ; keep rows 0-7 (lq<2)
    if (lq < 2) {
#pragma unroll
      for (int a = 0; a < 4; ++a)
#pragma unroll
        for (int r = 0; r < 4; ++r)
          gpart[kq][lq * 4 + r][nh * 64 + a * 16 + l15] = acc[a][r];
    }
    __syncthreads();

    if (tid < 256) {
      float gi = bs0, gf = bs1, gg = bs2, go = bs3;
#pragma unroll
      for (int q = 0; q < 4; ++q) {
        gi += gpart[q][m_loc][j];
        gf += gpart[q][m_loc][32 + j];
        gg += gpart[q][m_loc][64 + j];
        go += gpart[q][m_loc][96 + j];
      }
      const float iv = sigm(gi), fv = sigm(gf), gv = tanh_fast(gg), ov = sigm(go);
      c_reg = fv * c_reg + iv * gv;
      const float hv = ov * tanh_fast(c_reg);

      // ---- packed double-publish, parity bit14 tag on every short ----
      const unsigned tagm = ((t >> 1) & 1) ? 0x4000u : 0u;
      const unsigned hb = (unsigned)f2bf(hv) | tagm;   // |hv|<1: bit14 free
      const int base = lane & 56;
      intx4 pk;
#pragma unroll
      for (int k = 0; k < 4; ++k) {
        const unsigned lo = (unsigned)__shfl((int)hb, base + 2 * k, 64) & 0xFFFFu;
        const unsigned hi = (unsigned)__shfl((int)hb, base + 2 * k + 1, 64);
        pk[k] = (int)(lo | (hi << 16));
      }
      if ((tid & 7) == 0) {
        const int u8 = unit & ~7;
        if (placed) {
          // fast: plain store -> own XCD's L2 (write-through L1)
          *(intx4*)(hx + ((size_t)((t & 1) * 8 + xg)) * 8192 + (size_t)m_loc * 1024 + u8) = pk;
        }
        // guaranteed: MALL copy (R8 protocol)
        unsigned short* hp = hbuf + (t & 1) * 65536 + (size_t)row_g * 1024 + u8;
        asm volatile("global_store_dwordx4 %0, %1, off sc0 sc1"
                     :: "v"(hp), "v"(pk) : "memory");
      }
      call[((size_t)t * 64 + row_g) * 1024 + unit] = f2bf(c_reg);
    }
    // gpart barrier above guards next iteration's hlds overwrite.
  }
}

// ---------------- output head: logits + softmax, fully parallel over t ----------------
__global__ __launch_bounds__(256, 1) void lstm_head(
    const unsigned short* __restrict__ call,
    const unsigned short* __restrict__ wout,
    const float* __restrict__ bout,
    float* __restrict__ out)
{
  const int tb = blockIdx.x;
  const int lane = threadIdx.x & 63;
  const int wv = threadIdx.x >> 6;
  const int l15 = lane & 15, lq = lane >> 4;

  __shared__ float sred[2][4][64];

  floatx4 zero = {0.f, 0.f, 0.f, 0.f};
  floatx4 acc[4][8];
#pragma unroll
  for (int mt = 0; mt < 4; ++mt)
#pragma unroll
    for (int nt = 0; nt < 8; ++nt) acc[mt][nt] = zero;

  const unsigned short* abase = call + ((size_t)tb * 64 + l15) * 1024 + lq * 8;
  const unsigned short* bbase = wout + ((size_t)(wv * 128 + l15)) * 1024 + lq * 8;

#pragma unroll 2
  for (int ks = 0; ks < 32; ++ks) {
    bf16x8 a[4];
#pragma unroll
    for (int mt = 0; mt < 4; ++mt)
      a[mt] = *(const bf16x8*)(abase + (size_t)mt * 16 * 1024 + ks * 32);
#pragma unroll
    for (int nt = 0; nt < 8; ++nt) {
      const bf16x8 b = *(const bf16x8*)(bbase + (size_t)nt * 16 * 1024 + ks * 32);
#pragma unroll
      for (int mt = 0; mt < 4; ++mt)
        acc[mt][nt] = __builtin_amdgcn_mfma_f32_16x16x32_bf16(a[mt], b, acc[mt][nt], 0, 0, 0);
    }
  }

#pragma unroll
  for (int nt = 0; nt < 8; ++nt) {
    const float bo = bout[wv * 128 + nt * 16 + l15];
#pragma unroll
    for (int mt = 0; mt < 4; ++mt)
#pragma unroll
      for (int r = 0; r < 4; ++r) acc[mt][nt][r] += bo;
  }

  float rmax[4][4];
#pragma unroll
  for (int mt = 0; mt < 4; ++mt)
#pragma unroll
    for (int r = 0; r < 4; ++r) {
      float m = acc[mt][0][r];
#pragma unroll
      for (int nt = 1; nt < 8; ++nt) m = fmaxf(m, acc[mt][nt][r]);
      m = fmaxf(m, __shfl_xor(m, 1, 64));
      m = fmaxf(m, __shfl_xor(m, 2, 64));
      m = fmaxf(m, __shfl_xor(m, 4, 64));
      m = fmaxf(m, __shfl_xor(m, 8, 64));
      rmax[mt][r] = m;
    }
  if (l15 == 0) {
#pragma unroll
    for (int mt = 0; mt < 4; ++mt)
#pragma unroll
      for (int r = 0; r < 4; ++r) sred[0][wv][mt * 16 + lq * 4 + r] = rmax[mt][r];
  }
  __syncthreads();
  float gmax[4][4], rsum[4][4];
#pragma unroll
  for (int mt = 0; mt < 4; ++mt)
#pragma unroll
    for (int r = 0; r < 4; ++r) {
      const int rw = mt * 16 + lq * 4 + r;
      gmax[mt][r] = fmaxf(fmaxf(sred[0][0][rw], sred[0][1][rw]),
                          fmaxf(sred[0][2][rw], sred[0][3][rw]));
      rsum[mt][r] = 0.f;
    }
#pragma unroll
  for (int mt = 0; mt < 4; ++mt)
#pragma unroll
    for (int nt = 0; nt < 8; ++nt)
#pragma unroll
      for (int r = 0; r < 4; ++r) {
        const float e = __expf(acc[mt][nt][r] - gmax[mt][r]);
        acc[mt][nt][r] = e;
        rsum[mt][r] += e;
      }
#pragma unroll
  for (int mt = 0; mt < 4; ++mt)
#pragma unroll
    for (int r = 0; r < 4; ++r) {
      float s = rsum[mt][r];
      s += __shfl_xor(s, 1, 64);
      s += __shfl_xor(s, 2, 64);
      s += __shfl_xor(s, 4, 64);
      s += __shfl_xor(s, 8, 64);
      rsum[mt][r] = s;
    }
  if (l15 == 0) {
#pragma unroll
    for (int mt = 0; mt < 4; ++mt)
#pragma unroll
      for (int r = 0; r < 4; ++r) sred[1][wv][mt * 16 + lq * 4 + r] = rsum[mt][r];
  }
  __syncthreads();
#pragma unroll
  for (int mt = 0; mt < 4; ++mt)
#pragma unroll
    for (int r = 0; r < 4; ++r) {
      const int rw = mt * 16 + lq * 4 + r;
      const float inv = 1.0f / (sred[1][0][rw] + sred[1][1][rw] +
                                sred[1][2][rw] + sred[1][3][rw]);
      float* orow = out + ((size_t)tb * 64 + rw) * 512 + wv * 128 + l15;
#pragma unroll
      for (int nt = 0; nt < 8; ++nt) orow[nt * 16] = acc[mt][nt][r] * inv;
    }
}

// ---------------- launch ----------------
extern "C" void kernel_launch(void* const* d_in, const int* in_sizes, int n_in,
                              void* d_out, int out_size, void* d_ws, size_t ws_size,
                              hipStream_t stream) {
  const float* x    = (const float*)d_in[0];
  const float* Wih  = (const float*)d_in[1];
  const float* Whh  = (const float*)d_in[2];
  const float* bih  = (const float*)d_in[3];
  const float* bhh  = (const float*)d_in[4];
  const float* Wout = (const float*)d_in[5];
  const float* bout = (const float*)d_in[6];
  const float* h0   = (const float*)d_in[7];
  const float* c0   = (const float*)d_in[8];
  float* out = (float*)d_out;

  char* ws = (char*)d_ws;
  unsigned short* hbuf  = (unsigned short*)(ws + 4096);         //   256 KB (MALL)
  unsigned short* woutb = (unsigned short*)(ws + 266240);       //     1 MB
  unsigned short* xT    = (unsigned short*)(ws + 1314816);      //    16 MB
  unsigned short* call  = (unsigned short*)(ws + 18092032);     //    32 MB
  unsigned short* hx    = (unsigned short*)(ws + 51646464);     //   256 KB (L2 ring)

  // poison: 0xFFFF has bit14=1 != parity tag 0 expected at first polls.
  // (memsets run every launch, incl. rocprof replays -> clean initial state.)
  hipMemsetAsync(hbuf, 0xFF, 262144, stream);
  hipMemsetAsync(hx, 0xFF, 262144, stream);
  cvt_w<<<256, 256, 0, stream>>>(Wout, woutb);
  transpose_x<<<dim3(8, 16, 64), 256, 0, stream>>>(x, xT);
  lstm_rec<<<256, 512, 0, stream>>>(Whh, Wih, bih, bhh, h0, c0, xT, hbuf, hx, call);
  lstm_head<<<256, 256, 0, stream>>>(call, woutb, bout, out);
}

// Round 9
// 1830.062 us; speedup vs baseline: 1.1846x; 1.0018x over previous
//
#include <hip/hip_runtime.h>

// LSTM_27152783245909 — persistent-recurrence LSTM for MI355X (gfx950)
// R12: self-TESTED intra-XCD ring + restored register economy.
//  * Partition: xg=blockIdx&7 owns batch rows [8xg,8xg+8); ngb=blockIdx>>3
//    owns units [32ngb,32ngb+32) (128 gate cols). 1024 threads = 16 waves
//    (nc col-quarter x kq K-quarter) -> 96 weight VGPRs/lane (R9 economy;
//    R10/R11's 192 caused scratch spill: FETCH/WRITE ballooned).
//    16 waves x <=128 VGPR forces 1 block/CU -> exactly 32 blocks/XCD.
//  * Mapping self-test: each block plain-stores a marker; wave0 sc0-reads
//    all 32 group markers (bounded). Plain stores are visible to sc0
//    readers ONLY same-XCD (dirty-in-L2 otherwise) -> test passes iff the
//    group truly shares an XCD. Pass -> ring mode; fail -> MALL mode.
//  * Ring (hx, 2-slot, 32KB/XCD, L2-resident): plain-store publish, sc0
//    polls, parity bit14 tags. ALL ring waits bounded (gate 64, bulk 24,
//    per-granule MALL fallback; 2 gate fails -> sticky MALL).
//  * MALL path (R4-R9 proven): producers ALWAYS double-publish sc0sc1 to
//    hbuf; unbounded waits live only there. No atomics, no election ->
//    replay-safe; liveness unconditional.

#define T_ 256
#define GATE_FAST 64
#define BULK_FAST 24
#define MARKER_ROUNDS 320

typedef __attribute__((ext_vector_type(8))) short bf16x8;
typedef __attribute__((ext_vector_type(4))) float floatx4;
typedef __attribute__((ext_vector_type(4))) int intx4;

__device__ __forceinline__ unsigned short f2bf(float f) {
  unsigned u = __builtin_bit_cast(unsigned, f);
  u += 0x7FFFu + ((u >> 16) & 1u);   // round-nearest-even
  return (unsigned short)(u >> 16);
}

__device__ __forceinline__ float sigm(float x) { return 1.0f / (1.0f + __expf(-x)); }
__device__ __forceinline__ float tanh_fast(float x) {
  return __builtin_fmaf(2.f, sigm(2.f * x), -1.f);
}

// ---------------- W_out fp32 -> bf16 (512x1024) ----------------
__global__ void cvt_w(const float* __restrict__ w, unsigned short* __restrict__ o) {
  const size_t g = (size_t)blockIdx.x * 256 + threadIdx.x;
  const float* s = w + g * 8;
  bf16x8 v;
#pragma unroll
  for (int i = 0; i < 8; ++i) v[i] = (short)f2bf(s[i]);
  *(bf16x8*)(o + g * 8) = v;
}

// ---------------- x[B=64, I=512, T=256] fp32 -> xT[T,B,I] bf16 ----------------
__global__ void transpose_x(const float* __restrict__ x, unsigned short* __restrict__ xT) {
  __shared__ float tile[32][33];
  const int b = blockIdx.z, i0 = blockIdx.y * 32, t0 = blockIdx.x * 32;
  const int tx = threadIdx.x & 31, ty = threadIdx.x >> 5;
#pragma unroll
  for (int p = 0; p < 4; ++p) {
    const int i = ty + p * 8;
    tile[i][tx] = x[((size_t)b * 512 + i0 + i) * 256 + t0 + tx];
  }
  __syncthreads();
#pragma unroll
  for (int p = 0; p < 4; ++p) {
    const int t = ty + p * 8;
    xT[((size_t)(t0 + t) * 64 + b) * 512 + i0 + tx] = f2bf(tile[tx][t]);
  }
}

// ---------------- persistent recurrence ----------------
// 256 blocks x 1024 thr (16 waves), 1 block/CU (forced by 16w x 128 VGPR).
// Wave wv: nc = wv&3 (gate = col-quarter, 32 units), kq = wv>>2 (K quarter).
__global__ __launch_bounds__(1024, 1) void lstm_rec(
    const float* __restrict__ Whh, const float* __restrict__ Wih,
    const float* __restrict__ bih, const float* __restrict__ bhh,
    const float* __restrict__ h0, const float* __restrict__ c0,
    const unsigned short* __restrict__ xT,
    unsigned short* __restrict__ hbuf,   // [2][64][1024] bf16 MALL (sc0sc1)
    unsigned short* __restrict__ hx,     // [2][8][8][1024] bf16 ring (plain/sc0)
    unsigned* __restrict__ ctrl,         // markers at +256 ints
    unsigned short* __restrict__ call)   // [256][64][1024] bf16
{
  const int tid = threadIdx.x;
  const int lane = tid & 63;
  const int wv = tid >> 6;            // 0..15
  const int nc = wv & 3, kq = wv >> 2;
  const int xg = blockIdx.x & 7;      // group: batch rows [8xg, 8xg+8)
  const int ngb = blockIdx.x >> 3;    // units [32ngb, 32ngb+32)
  const int l15 = lane & 15, lq = lane >> 4;
  const int hrow = l15 & 7;           // A rows 8-15 duplicate 0-7

  __shared__ unsigned short hlds[8 * 1032];   // 8 rows, stride 1032
  __shared__ float gpart[4][8][132];          // [kq][row][col 0..127]
  __shared__ int s_mode;                      // 0 = ring, 1 = MALL
  __shared__ int s_gate;                      // this-step ring-gate timeout
  __shared__ int s_fails;

  // ---- marker publish (plain store -> own XCD L2) ----
  if (tid == 0) {
    s_gate = 0; s_fails = 0;
    *((volatile int*)(ctrl + 256 + xg * 32 + ngb)) = (int)(blockIdx.x + 1);
  }

  // ---- persistent B fragments: 2 tiles x 12 ksteps = 96 VGPRs/lane ----
  // col c = nc*32 + a*16 + l15 -> gate nc, unit a*16+l15;
  // weight col = nc*1024 + ngb*32 + (a*16+l15). K: [0,1024)=Whh, rest=Wih.
  bf16x8 bfrag[2][12];
#pragma unroll
  for (int a = 0; a < 2; ++a) {
    const int wcol = nc * 1024 + ngb * 32 + a * 16 + l15;
#pragma unroll
    for (int ks = 0; ks < 12; ++ks) {
      const int kg = kq * 384 + ks * 32 + lq * 8;   // never straddles 1024
      const float* s = (kg < 1024) ? (Whh + (size_t)wcol * 1024 + kg)
                                   : (Wih + (size_t)wcol * 512 + (kg - 1024));
      bf16x8 v;
#pragma unroll
      for (int i = 0; i < 8; ++i) v[i] = (short)f2bf(s[i]);
      bfrag[a][ks] = v;
    }
  }

  // per-thread cell state (tid<256): cell (m_loc, j)
  const int m_loc = tid >> 5, j = tid & 31;
  const int row_g = xg * 8 + m_loc;
  const int unit = ngb * 32 + j;
  float c_reg = 0.f, bs0 = 0.f, bs1 = 0.f, bs2 = 0.f, bs3 = 0.f;
  if (tid < 256) {
    c_reg = c0[unit];
    bs0 = bih[unit] + bhh[unit];
    bs1 = bih[1024 + unit] + bhh[1024 + unit];
    bs2 = bih[2048 + unit] + bhh[2048 + unit];
    bs3 = bih[3072 + unit] + bhh[3072 + unit];
  }

  // ---- mapping self-test: see all 32 group markers via sc0? ----
  if (wv == 0) {
    int ok = 0;
    const int* mp = (const int*)(ctrl + 256 + xg * 32 + (lane & 31));
    for (int r = 0; r < MARKER_ROUNDS; ++r) {
      int m;
      asm volatile("global_load_dword %0, %1, off sc0\n\ts_waitcnt vmcnt(0)"
                   : "=v"(m) : "v"(mp) : "memory");
      if (__all(lane < 32 ? (m != 0) : true)) { ok = 1; break; }
      __builtin_amdgcn_s_sleep(2);
    }
    if (lane == 0) s_mode = ok ? 0 : 1;
  }
  __syncthreads();

  for (int t = 0; t < T_; ++t) {
    floatx4 zero = {0.f, 0.f, 0.f, 0.f};
    floatx4 acc0 = zero, acc1 = zero;

    // ---- x-part (independent of h_{t-1}; overlaps peers' publishes) ----
    const unsigned short* bx = xT + ((size_t)t * 64 + xg * 8 + hrow) * 512;
#pragma unroll
    for (int ks = 0; ks < 12; ++ks) {
      const int kg = kq * 384 + ks * 32 + lq * 8;
      if (kg >= 1024) {
        const bf16x8 af = *(const bf16x8*)(bx + (kg - 1024));
        acc0 = __builtin_amdgcn_mfma_f32_16x16x32_bf16(af, bfrag[0][ks], acc0, 0, 0, 0);
        acc1 = __builtin_amdgcn_mfma_f32_16x16x32_bf16(af, bfrag[1][ks], acc1, 0, 0, 0);
      }
    }

    // ---- acquire h_{t-1}[8][1024] -> hlds ----
    const int slot = (t + 1) & 1;
    const unsigned tagpat = (((t - 1) >> 1) & 1) ? 0x40004000u : 0u;
    const unsigned short* rbase = hx + (size_t)(slot * 8 + xg) * 8192;
    const unsigned short* mbase = hbuf + (size_t)slot * 65536 + (size_t)(xg * 8) * 1024;

    if (t > 0) {
      // gate phase
      if (s_mode == 0) {
        if (wv == 0) {
          int ok = 0;
          const unsigned short* sp = rbase + (size_t)(lane & 31) * 32;
          for (int r = 0; r < GATE_FAST; ++r) {
            intx4 sv;
            asm volatile("global_load_dwordx4 %0, %1, off sc0\n\ts_waitcnt vmcnt(0)"
                         : "=v"(sv) : "v"(sp) : "memory");
            unsigned bad = 0;
#pragma unroll
            for (int d = 0; d < 4; ++d) bad |= ((unsigned)sv[d] ^ tagpat) & 0x40004000u;
            if (__all(lane < 32 ? (bad == 0) : true)) { ok = 1; break; }
            __builtin_amdgcn_s_sleep(1);
          }
          if (lane == 0 && !ok) s_gate = 1;
        }
      } else {
        if (wv == 0) {
          const unsigned short* sp = mbase + (size_t)(lane & 31) * 32;
          while (true) {
            intx4 sv;
            asm volatile("global_load_dwordx4 %0, %1, off sc0 sc1\n\ts_waitcnt vmcnt(0)"
                         : "=v"(sv) : "v"(sp) : "memory");
            unsigned bad = 0;
#pragma unroll
            for (int d = 0; d < 4; ++d) bad |= ((unsigned)sv[d] ^ tagpat) & 0x40004000u;
            if (__all(lane < 32 ? (bad == 0) : true)) break;
            __builtin_amdgcn_s_sleep(1);
          }
        }
      }
    }
    __syncthreads();   // bar#1

    if (t == 0) {
      // h_{-1} = h0 broadcast (fp32 input; bypasses tag paths)
      const int row8 = tid >> 7, colu = (tid & 127) * 8;
      const float* s = h0 + colu;
      bf16x8 v;
#pragma unroll
      for (int i = 0; i < 8; ++i) v[i] = (short)f2bf(s[i]);
      *(bf16x8*)(hlds + row8 * 1032 + colu) = v;
    } else {
      const bool usemall = (s_mode != 0) || (s_gate != 0);
      const int row8 = tid >> 7, colu = (tid & 127) * 8;
      intx4 v;
      bool got = false;
      if (!usemall) {
        const unsigned short* rp = rbase + (size_t)row8 * 1024 + colu;
        for (int r = 0; r < BULK_FAST; ++r) {
          asm volatile("global_load_dwordx4 %0, %1, off sc0\n\ts_waitcnt vmcnt(0)"
                       : "=v"(v) : "v"(rp) : "memory");
          unsigned bad = 0;
#pragma unroll
          for (int d = 0; d < 4; ++d) bad |= ((unsigned)v[d] ^ tagpat) & 0x40004000u;
          if (!bad) { got = true; break; }
          __builtin_amdgcn_s_sleep(1);
        }
      }
      if (!got) {
        // MALL (proven live: producers always publish hbuf)
        const unsigned short* mp = mbase + (size_t)row8 * 1024 + colu;
        while (true) {
          asm volatile("global_load_dwordx4 %0, %1, off sc0 sc1\n\ts_waitcnt vmcnt(0)"
                       : "=v"(v) : "v"(mp) : "memory");
          unsigned bad = 0;
#pragma unroll
          for (int d = 0; d < 4; ++d) bad |= ((unsigned)v[d] ^ tagpat) & 0x40004000u;
          if (!bad) break;
          __builtin_amdgcn_s_sleep(1);
        }
      }
#pragma unroll
      for (int d = 0; d < 4; ++d) v[d] &= (int)0xBFFFBFFFu;   // strip tags
      *(intx4*)(hlds + row8 * 1032 + colu) = v;
      // bookkeeping (tid 0 only; ordered for next step by bar#2)
      if (tid == 0) {
        if (s_mode == 0 && s_gate) { if (++s_fails >= 2) s_mode = 1; }
        s_gate = 0;
      }
    }
    __syncthreads();   // bar#2

    // ---- h-part MFMAs from LDS ----
#pragma unroll
    for (int ks = 0; ks < 12; ++ks) {
      const int kg = kq * 384 + ks * 32 + lq * 8;
      if (kg < 1024) {
        const bf16x8 af = *(const bf16x8*)(hlds + hrow * 1032 + kg);
        acc0 = __builtin_amdgcn_mfma_f32_16x16x32_bf16(af, bfrag[0][ks], acc0, 0, 0, 0);
        acc1 = __builtin_amdgcn_mfma_f32_16x16x32_bf16(af, bfrag[1][ks], acc1, 0, 0, 0);
      }
    }

    // C layout: col = lane&15, row = (lane>>4)*4 + r ; keep rows 0-7 (lq<2)
    if (lq < 2) {
#pragma unroll
      for (int r = 0; r < 4; ++r) {
        gpart[kq][lq * 4 + r][nc * 32 + l15]      = acc0[r];
        gpart[kq][lq * 4 + r][nc * 32 + 16 + l15] = acc1[r];
      }
    }
    __syncthreads();   // bar#3

    if (tid < 256) {
      float gi = bs0, gf = bs1, gg = bs2, go = bs3;
#pragma unroll
      for (int q = 0; q < 4; ++q) {
        gi += gpart[q][m_loc][j];
        gf += gpart[q][m_loc][32 + j];
        gg += gpart[q][m_loc][64 + j];
        go += gpart[q][m_loc][96 + j];
      }
      const float iv = sigm(gi), fv = sigm(gf), gv = tanh_fast(gg), ov = sigm(go);
      c_reg = fv * c_reg + iv * gv;
      const float hv = ov * tanh_fast(c_reg);

      // ---- packed double-publish, parity bit14 tag on every short ----
      const unsigned tagm = ((t >> 1) & 1) ? 0x4000u : 0u;
      const unsigned hb = (unsigned)f2bf(hv) | tagm;   // |hv|<1: bit14 free
      const int base = lane & 56;
      intx4 pk;
#pragma unroll
      for (int k = 0; k < 4; ++k) {
        const unsigned lo = (unsigned)__shfl((int)hb, base + 2 * k, 64) & 0xFFFFu;
        const unsigned hi = (unsigned)__shfl((int)hb, base + 2 * k + 1, 64);
        pk[k] = (int)(lo | (hi << 16));
      }
      if ((tid & 7) == 0) {
        const int u8 = unit & ~7;
        if (s_mode == 0) {
          // fast: plain store -> own XCD's L2
          *(intx4*)(hx + (size_t)((t & 1) * 8 + xg) * 8192 + (size_t)m_loc * 1024 + u8) = pk;
        }
        // guaranteed: MALL copy (proven protocol)
        unsigned short* hp = hbuf + (size_t)(t & 1) * 65536 + (size_t)row_g * 1024 + u8;
        asm volatile("global_store_dwordx4 %0, %1, off sc0 sc1"
                     :: "v"(hp), "v"(pk) : "memory");
      }
      call[((size_t)t * 64 + row_g) * 1024 + unit] = f2bf(c_reg);
    }
    // bar#1 of next step guards hlds/gpart reuse.
  }
}

// ---------------- output head: logits + softmax, fully parallel over t ----------------
__global__ __launch_bounds__(256, 1) void lstm_head(
    const unsigned short* __restrict__ call,
    const unsigned short* __restrict__ wout,
    const float* __restrict__ bout,
    float* __restrict__ out)
{
  const int tb = blockIdx.x;
  const int lane = threadIdx.x & 63;
  const int wv = threadIdx.x >> 6;
  const int l15 = lane & 15, lq = lane >> 4;

  __shared__ float sred[2][4][64];

  floatx4 zero = {0.f, 0.f, 0.f, 0.f};
  floatx4 acc[4][8];
#pragma unroll
  for (int mt = 0; mt < 4; ++mt)
#pragma unroll
    for (int nt = 0; nt < 8; ++nt) acc[mt][nt] = zero;

  const unsigned short* abase = call + ((size_t)tb * 64 + l15) * 1024 + lq * 8;
  const unsigned short* bbase = wout + ((size_t)(wv * 128 + l15)) * 1024 + lq * 8;

#pragma unroll 2
  for (int ks = 0; ks < 32; ++ks) {
    bf16x8 a[4];
#pragma unroll
    for (int mt = 0; mt < 4; ++mt)
      a[mt] = *(const bf16x8*)(abase + (size_t)mt * 16 * 1024 + ks * 32);
#pragma unroll
    for (int nt = 0; nt < 8; ++nt) {
      const bf16x8 b = *(const bf16x8*)(bbase + (size_t)nt * 16 * 1024 + ks * 32);
#pragma unroll
      for (int mt = 0; mt < 4; ++mt)
        acc[mt][nt] = __builtin_amdgcn_mfma_f32_16x16x32_bf16(a[mt], b, acc[mt][nt], 0, 0, 0);
    }
  }

#pragma unroll
  for (int nt = 0; nt < 8; ++nt) {
    const float bo = bout[wv * 128 + nt * 16 + l15];
#pragma unroll
    for (int mt = 0; mt < 4; ++mt)
#pragma unroll
      for (int r = 0; r < 4; ++r) acc[mt][nt][r] += bo;
  }

  float rmax[4][4];
#pragma unroll
  for (int mt = 0; mt < 4; ++mt)
#pragma unroll
    for (int r = 0; r < 4; ++r) {
      float m = acc[mt][0][r];
#pragma unroll
      for (int nt = 1; nt < 8; ++nt) m = fmaxf(m, acc[mt][nt][r]);
      m = fmaxf(m, __shfl_xor(m, 1, 64));
      m = fmaxf(m, __shfl_xor(m, 2, 64));
      m = fmaxf(m, __shfl_xor(m, 4, 64));
      m = fmaxf(m, __shfl_xor(m, 8, 64));
      rmax[mt][r] = m;
    }
  if (l15 == 0) {
#pragma unroll
    for (int mt = 0; mt < 4; ++mt)
#pragma unroll
      for (int r = 0; r < 4; ++r) sred[0][wv][mt * 16 + lq * 4 + r] = rmax[mt][r];
  }
  __syncthreads();
  float gmax[4][4], rsum[4][4];
#pragma unroll
  for (int mt = 0; mt < 4; ++mt)
#pragma unroll
    for (int r = 0; r < 4; ++r) {
      const int rw = mt * 16 + lq * 4 + r;
      gmax[mt][r] = fmaxf(fmaxf(sred[0][0][rw], sred[0][1][rw]),
                          fmaxf(sred[0][2][rw], sred[0][3][rw]));
      rsum[mt][r] = 0.f;
    }
#pragma unroll
  for (int mt = 0; mt < 4; ++mt)
#pragma unroll
    for (int nt = 0; nt < 8; ++nt)
#pragma unroll
      for (int r = 0; r < 4; ++r) {
        const float e = __expf(acc[mt][nt][r] - gmax[mt][r]);
        acc[mt][nt][r] = e;
        rsum[mt][r] += e;
      }
#pragma unroll
  for (int mt = 0; mt < 4; ++mt)
#pragma unroll
    for (int r = 0; r < 4; ++r) {
      float s = rsum[mt][r];
      s += __shfl_xor(s, 1, 64);
      s += __shfl_xor(s, 2, 64);
      s += __shfl_xor(s, 4, 64);
      s += __shfl_xor(s, 8, 64);
      rsum[mt][r] = s;
    }
  if (l15 == 0) {
#pragma unroll
    for (int mt = 0; mt < 4; ++mt)
#pragma unroll
      for (int r = 0; r < 4; ++r) sred[1][wv][mt * 16 + lq * 4 + r] = rsum[mt][r];
  }
  __syncthreads();
#pragma unroll
  for (int mt = 0; mt < 4; ++mt)
#pragma unroll
    for (int r = 0; r < 4; ++r) {
      const int rw = mt * 16 + lq * 4 + r;
      const float inv = 1.0f / (sred[1][0][rw] + sred[1][1][rw] +
                                sred[1][2][rw] + sred[1][3][rw]);
      float* orow = out + ((size_t)tb * 64 + rw) * 512 + wv * 128 + l15;
#pragma unroll
      for (int nt = 0; nt < 8; ++nt) orow[nt * 16] = acc[mt][nt][r] * inv;
    }
}

// ---------------- launch ----------------
extern "C" void kernel_launch(void* const* d_in, const int* in_sizes, int n_in,
                              void* d_out, int out_size, void* d_ws, size_t ws_size,
                              hipStream_t stream) {
  const float* x    = (const float*)d_in[0];
  const float* Wih  = (const float*)d_in[1];
  const float* Whh  = (const float*)d_in[2];
  const float* bih  = (const float*)d_in[3];
  const float* bhh  = (const float*)d_in[4];
  const float* Wout = (const float*)d_in[5];
  const float* bout = (const float*)d_in[6];
  const float* h0   = (const float*)d_in[7];
  const float* c0   = (const float*)d_in[8];
  float* out = (float*)d_out;

  char* ws = (char*)d_ws;
  unsigned* ctrl        = (unsigned*)(ws + 0);                  //     4 KB (markers)
  unsigned short* hbuf  = (unsigned short*)(ws + 4096);         //   256 KB (MALL)
  unsigned short* woutb = (unsigned short*)(ws + 266240);       //     1 MB
  unsigned short* xT    = (unsigned short*)(ws + 1314816);      //    16 MB
  unsigned short* call  = (unsigned short*)(ws + 18092032);     //    32 MB
  unsigned short* hx    = (unsigned short*)(ws + 51646464);     //   256 KB (ring)

  // per-launch clean state (runs in every rocprof replay iteration too):
  hipMemsetAsync(ctrl, 0, 4096, stream);        // markers = 0
  hipMemsetAsync(hbuf, 0xFF, 262144, stream);   // bit14=1 poison
  hipMemsetAsync(hx, 0xFF, 262144, stream);
  cvt_w<<<256, 256, 0, stream>>>(Wout, woutb);
  transpose_x<<<dim3(8, 16, 64), 256, 0, stream>>>(x, xT);
  lstm_rec<<<256, 1024, 0, stream>>>(Whh, Wih, bih, bhh, h0, c0, xT, hbuf, hx, ctrl, call);
  lstm_head<<<256, 256, 0, stream>>>(call, woutb, bout, out);
}